// Round 6
// baseline (764.740 us; speedup 1.0000x reference)
//
#include <hip/hip_runtime.h>

#define BB 32
#define NN 512
#define EE 256
#define HH 8
#define HDD 32

typedef __attribute__((ext_vector_type(4))) float f32x4;
typedef __attribute__((ext_vector_type(8))) short s16x8;
typedef unsigned short ushort_t;
typedef unsigned int uint_t;
typedef unsigned long long ull_t;

__device__ __forceinline__ ushort_t f2bf(float f) {
  union { float f; uint_t u; } v; v.f = f;
  uint_t r = v.u + 0x7fffu + ((v.u >> 16) & 1u);
  return (ushort_t)(r >> 16);
}
__device__ __forceinline__ uint_t pk2(float a, float b) {
  return (uint_t)f2bf(a) | ((uint_t)f2bf(b) << 16);
}
__device__ __forceinline__ float bf2f(ushort_t u) {
  union { uint_t u; float f; } v; v.u = ((uint_t)u) << 16;
  return v.f;
}

// ---------------- Kernel 0: fp32 -> bf16 convert (x, in_w, out_w in one grid) ----------------
__global__ __launch_bounds__(256) void cvt_all(
    const float* __restrict__ x, const float* __restrict__ w1, const float* __restrict__ w2,
    ushort_t* __restrict__ xb, ushort_t* __restrict__ w1b, ushort_t* __restrict__ w2b) {
  const int NX = BB * NN * EE / 4;     // 1048576
  const int NW1 = 3 * EE * EE / 4;     // 49152
  const int NW2 = EE * EE / 4;         // 16384
  int i = blockIdx.x * 256 + threadIdx.x;
  const float* src; ushort_t* dst; int j;
  if (i < NX) { src = x; dst = xb; j = i; }
  else if (i < NX + NW1) { src = w1; dst = w1b; j = i - NX; }
  else if (i < NX + NW1 + NW2) { src = w2; dst = w2b; j = i - NX - NW1; }
  else return;
  float4 v = ((const float4*)src)[j];
  uint2 p; p.x = pk2(v.x, v.y); p.y = pk2(v.z, v.w);
  ((uint2*)dst)[j] = p;
}

// ---------------- Kernel 1: QKV projection (bf16 MFMA GEMM) + mask bit-compress ----------------
// 128x128 tile, 4 waves 2x2, BK=32. Q,K head-major [B,H,N,32]; V transposed [B,H,32,N].
// Interleaved: 3072 waves ballot-pack the 67.1M-int pre_mask into 8.4 MB of bits,
// 43 words per wave per K-step (8 steps) so the 268 MB stream overlaps MFMA.
__global__ __launch_bounds__(256) void qkv_mfma(
    const ushort_t* __restrict__ xb, const ushort_t* __restrict__ wb,
    const float* __restrict__ bias,
    ushort_t* __restrict__ Q, ushort_t* __restrict__ K, ushort_t* __restrict__ Vt,
    const int* __restrict__ pre_mask, ull_t* __restrict__ mbits) {
  __shared__ ushort_t sA[128][40];
  __shared__ ushort_t sB[128][40];
  int t = threadIdx.x;
  int bj = blockIdx.x % 6, bm = blockIdx.x / 6;
  int m0 = bm * 128, j0 = bj * 128;
  int w4 = t >> 6, lane = t & 63, quad = lane >> 4, l16 = lane & 15;
  int wy = w4 >> 1, wx = w4 & 1;
  int wid = blockIdx.x * 4 + w4;     // 0..3071
  f32x4 acc[4][4];
  #pragma unroll
  for (int a = 0; a < 4; a++)
    #pragma unroll
    for (int b = 0; b < 4; b++) acc[a][b] = (f32x4){0.f, 0.f, 0.f, 0.f};
  int sr2 = t >> 2, sc2 = (t & 3) * 8;
  for (int ks = 0; ks < 8; ks++) {
    int kk = ks * 32;
    __syncthreads();
    #pragma unroll
    for (int p = 0; p < 2; p++) {
      int r = sr2 + 64 * p;
      *(s16x8*)&sA[r][sc2] = *(const s16x8*)&xb[(size_t)(m0 + r) * 256 + kk + sc2];
      *(s16x8*)&sB[r][sc2] = *(const s16x8*)&wb[(size_t)(j0 + r) * 256 + kk + sc2];
    }
    __syncthreads();
    s16x8 af[4], bf[4];
    #pragma unroll
    for (int mt = 0; mt < 4; mt++)
      af[mt] = *(const s16x8*)&sA[wy * 64 + mt * 16 + l16][quad * 8];
    #pragma unroll
    for (int jt = 0; jt < 4; jt++)
      bf[jt] = *(const s16x8*)&sB[wx * 64 + jt * 16 + l16][quad * 8];
    #pragma unroll
    for (int mt = 0; mt < 4; mt++)
      #pragma unroll
      for (int jt = 0; jt < 4; jt++)
        acc[mt][jt] = __builtin_amdgcn_mfma_f32_16x16x32_bf16(af[mt], bf[jt], acc[mt][jt], 0, 0, 0);
    // interleaved mask compress: overlap mask HBM stream with MFMA
    #pragma unroll 4
    for (int j = 0; j < 43; j++) {
      int widx = (ks * 43 + j) * 3072 + wid;
      if (widx < 1048576) {
        int mv = pre_mask[(size_t)widx * 64 + lane];
        ull_t bl = __ballot(mv != 0);
        if (lane == 0) mbits[widx] = bl;
      }
    }
  }
  #pragma unroll
  for (int jt = 0; jt < 4; jt++) {
    int j = j0 + wx * 64 + jt * 16 + l16;
    int which = j >> 8, e0 = j & 255, h = e0 >> 5, d0 = e0 & 31;
    float b = bias[j];
    #pragma unroll
    for (int mt = 0; mt < 4; mt++) {
      #pragma unroll
      for (int r = 0; r < 4; r++) {
        int m = m0 + wy * 64 + mt * 16 + quad * 4 + r;
        int bi = m >> 9, n = m & 511;
        ushort_t val = f2bf(acc[mt][jt][r] + b);
        if (which == 2) {
          Vt[((size_t)(bi * 8 + h) * 32 + d0) * 512 + n] = val;
        } else {
          ushort_t* dst = (which == 0) ? Q : K;
          dst[((size_t)(bi * 8 + h) * 512 + n) * 32 + d0] = val;
        }
      }
    }
  }
}

// ---------------- Kernel 2: fused attention + out-proj + mask + residual + LN ----------------
// block = (b, 16-q tile), 1024 blocks, 4 waves; wave w owns keys [w*128, w*128+128)
// Mask arrives as a bitfield: 4 broadcast uint4 loads/head replace 256 scalar dword loads.
__global__ __launch_bounds__(256, 4) void attn_fused(
    const ushort_t* __restrict__ Q, const ushort_t* __restrict__ K,
    const ushort_t* __restrict__ Vt, const uint_t* __restrict__ mbits32,
    const ushort_t* __restrict__ wob, const float* __restrict__ x,
    const float* __restrict__ out_b, const int* __restrict__ post_mask,
    const float* __restrict__ gamma, const float* __restrict__ beta,
    float* __restrict__ out, float* __restrict__ attnw) {
  __shared__ ushort_t sP[4][16 * 132];   // wave-private unnormalized e (bf16)
  __shared__ float sSum[2][4][16];       // double-buffered per-head row sums
  __shared__ float sO[4][16 * 33];       // per-wave PV partials
  __shared__ ushort_t sO16[16 * 260];    // assembled O tile (bf16, A-layout)
  __shared__ float sRed1[16][4];         // LN reduce
  __shared__ float sRed2[16][4];

  int t = threadIdx.x;
  int bb = blockIdx.x >> 5;
  int q0 = (blockIdx.x & 31) << 4;
  int w = t >> 6, lane = t & 63, quad = lane >> 4, l16 = lane & 15;
  int kbase = w * 128;
  const float scale = 0.17677669529663687f;  // 1/sqrt(32)
  ushort_t* mysP = &sP[w][0];

  // head-mean accumulators packed as bf16 pairs: wm[i*4+t4] = (t8=2*t4 | t8=2*t4+1)
  uint_t wm[16];
  #pragma unroll
  for (int i = 0; i < 16; i++) wm[i] = 0u;

  for (int h = 0; h < 8; h++) {
    size_t base = ((size_t)(bb * 8 + h) * 512) * 32;
    // bitmask row pointer: row r -> 16 uint32s; this wave's 128-bit slice at +kbase/32
    const uint_t* mb = mbits32 + ((size_t)(bb * 8 + h) * 512 + q0) * 16 + (kbase >> 5);

    // Q A-frag direct from global
    s16x8 afrag = *(const s16x8*)&Q[base + (size_t)(q0 + l16) * 32 + quad * 8];

    uint4 mrow[4];
    #pragma unroll
    for (int i = 0; i < 4; i++)
      mrow[i] = *(const uint4*)&mb[(quad * 4 + i) * 16];

    // ---- scores + exp + wave-private sP + partial sums ----
    float psum[4] = {0.f, 0.f, 0.f, 0.f};
    #pragma unroll
    for (int t8 = 0; t8 < 8; t8++) {
      int n0 = kbase + t8 * 16;
      s16x8 bfrag = *(const s16x8*)&K[base + (size_t)(n0 + l16) * 32 + quad * 8];
      f32x4 acc = {0.f, 0.f, 0.f, 0.f};
      acc = __builtin_amdgcn_mfma_f32_16x16x32_bf16(afrag, bfrag, acc, 0, 0, 0);
      int sh = (t8 & 1) * 16 + l16;
      #pragma unroll
      for (int i = 0; i < 4; i++) {
        uint_t sel = ((const uint_t*)&mrow[i])[t8 >> 1];
        float e = ((sel >> sh) & 1u) ? 0.f : __expf(acc[i] * scale);
        mysP[(quad * 4 + i) * 132 + t8 * 16 + l16] = f2bf(e);
        psum[i] += e;
      }
    }
    #pragma unroll
    for (int i = 0; i < 4; i++) {
      float s = psum[i];
      s += __shfl_xor(s, 1, 64);
      s += __shfl_xor(s, 2, 64);
      s += __shfl_xor(s, 4, 64);
      s += __shfl_xor(s, 8, 64);
      psum[i] = s;
    }
    if (l16 == 0) {
      #pragma unroll
      for (int i = 0; i < 4; i++) sSum[h & 1][w][quad * 4 + i] = psum[i];
    }
    __syncthreads();   // B2: sSum ready (also fences prior head's epilogue reads of sO)

    // ---- head-mean weights: re-read own sP, accumulate in packed bf16 ----
    float inv[4];
    #pragma unroll
    for (int i = 0; i < 4; i++) {
      int r = quad * 4 + i;
      inv[i] = 0.125f / (sSum[h & 1][0][r] + sSum[h & 1][1][r] + sSum[h & 1][2][r] + sSum[h & 1][3][r]);
    }
    #pragma unroll
    for (int i = 0; i < 4; i++) {
      #pragma unroll
      for (int t4 = 0; t4 < 4; t4++) {
        float a0 = inv[i] * bf2f(mysP[(quad * 4 + i) * 132 + (2 * t4) * 16 + l16]);
        float a1 = inv[i] * bf2f(mysP[(quad * 4 + i) * 132 + (2 * t4 + 1) * 16 + l16]);
        uint_t cur = wm[i * 4 + t4];
        wm[i * 4 + t4] = pk2(bf2f((ushort_t)(cur & 0xffffu)) + a0,
                             bf2f((ushort_t)(cur >> 16)) + a1);
      }
    }

    // ---- PV over own 128-k slice (unnormalized); wave-private sP, no barrier ----
    f32x4 oacc[2];
    oacc[0] = (f32x4){0.f, 0.f, 0.f, 0.f};
    oacc[1] = (f32x4){0.f, 0.f, 0.f, 0.f};
    #pragma unroll
    for (int ks = 0; ks < 4; ks++) {
      s16x8 pa = *(const s16x8*)&mysP[l16 * 132 + ks * 32 + quad * 8];
      #pragma unroll
      for (int dt = 0; dt < 2; dt++) {
        s16x8 vb = *(const s16x8*)&Vt[base + (size_t)(dt * 16 + l16) * 512 + kbase + ks * 32 + quad * 8];
        oacc[dt] = __builtin_amdgcn_mfma_f32_16x16x32_bf16(pa, vb, oacc[dt], 0, 0, 0);
      }
    }
    #pragma unroll
    for (int dt = 0; dt < 2; dt++)
      #pragma unroll
      for (int i = 0; i < 4; i++)
        sO[w][(quad * 4 + i) * 33 + dt * 16 + l16] = oacc[dt][i];
    __syncthreads();   // B3: sO ready

    // ---- combine waves, normalize, stash O tile in LDS (bf16 A-layout) ----
    {
      int r = t >> 4;
      int c = (t & 15) * 2;
      float s0 = sO[0][r * 33 + c] + sO[1][r * 33 + c] + sO[2][r * 33 + c] + sO[3][r * 33 + c];
      float s1 = sO[0][r * 33 + c + 1] + sO[1][r * 33 + c + 1] + sO[2][r * 33 + c + 1] + sO[3][r * 33 + c + 1];
      float invr = 1.0f / (sSum[h & 1][0][r] + sSum[h & 1][1][r] + sSum[h & 1][2][r] + sSum[h & 1][3][r]);
      *(uint_t*)&sO16[r * 260 + h * 32 + c] = pk2(s0 * invr, s1 * invr);
    }
  }

  // ---- head-averaged attention weights (unpack bf16 pairs) ----
  {
    float* arow = attnw + (size_t)(bb * 512 + q0) * 512;
    #pragma unroll
    for (int i = 0; i < 4; i++) {
      #pragma unroll
      for (int t4 = 0; t4 < 4; t4++) {
        uint_t c = wm[i * 4 + t4];
        arow[(quad * 4 + i) * 512 + kbase + (2 * t4) * 16 + l16] = bf2f((ushort_t)(c & 0xffffu));
        arow[(quad * 4 + i) * 512 + kbase + (2 * t4 + 1) * 16 + l16] = bf2f((ushort_t)(c >> 16));
      }
    }
  }
  __syncthreads();   // Bf: sO16 complete

  // ---- fused out-proj: wave w owns cols [w*64, w*64+64) ----
  int jr0 = w * 64;
  f32x4 pacc[4];
  #pragma unroll
  for (int jt = 0; jt < 4; jt++) pacc[jt] = (f32x4){0.f, 0.f, 0.f, 0.f};
  #pragma unroll
  for (int kc = 0; kc < 8; kc++) {
    s16x8 pa = *(const s16x8*)&sO16[l16 * 260 + kc * 32 + quad * 8];
    #pragma unroll
    for (int jt = 0; jt < 4; jt++) {
      s16x8 bf = *(const s16x8*)&wob[(size_t)(jr0 + jt * 16 + l16) * 256 + kc * 32 + quad * 8];
      pacc[jt] = __builtin_amdgcn_mfma_f32_16x16x32_bf16(pa, bf, pacc[jt], 0, 0, 0);
    }
  }

  // ---- post-mask + residual + LayerNorm ----
  float g4[4], bt4[4], ob4[4];
  #pragma unroll
  for (int jt = 0; jt < 4; jt++) {
    int j = jr0 + jt * 16 + l16;
    g4[jt] = gamma[j]; bt4[jt] = beta[j]; ob4[jt] = out_b[j];
  }
  float yv[4][4];
  #pragma unroll
  for (int i = 0; i < 4; i++) {
    int r = quad * 4 + i;
    int m = bb * 512 + q0 + r;
    bool msk = post_mask[m] != 0;
    float s1 = 0.f, s2 = 0.f;
    #pragma unroll
    for (int jt = 0; jt < 4; jt++) {
      int j = jr0 + jt * 16 + l16;
      float p = msk ? 0.f : (pacc[jt][i] + ob4[jt]);
      float yy = x[(size_t)m * 256 + j] + p;
      yv[i][jt] = yy; s1 += yy; s2 += yy * yy;
    }
    s1 += __shfl_xor(s1, 1, 64); s1 += __shfl_xor(s1, 2, 64);
    s1 += __shfl_xor(s1, 4, 64); s1 += __shfl_xor(s1, 8, 64);
    s2 += __shfl_xor(s2, 1, 64); s2 += __shfl_xor(s2, 2, 64);
    s2 += __shfl_xor(s2, 4, 64); s2 += __shfl_xor(s2, 8, 64);
    if (l16 == 0) { sRed1[r][w] = s1; sRed2[r][w] = s2; }
  }
  __syncthreads();
  #pragma unroll
  for (int i = 0; i < 4; i++) {
    int r = quad * 4 + i;
    int m = bb * 512 + q0 + r;
    float S1 = sRed1[r][0] + sRed1[r][1] + sRed1[r][2] + sRed1[r][3];
    float S2 = sRed2[r][0] + sRed2[r][1] + sRed2[r][2] + sRed2[r][3];
    float mu = S1 * (1.0f / 256.0f);
    float var = S2 * (1.0f / 256.0f) - mu * mu;
    float rstd = rsqrtf(var + 1e-5f);
    #pragma unroll
    for (int jt = 0; jt < 4; jt++) {
      int j = jr0 + jt * 16 + l16;
      out[(size_t)m * 256 + j] = (yv[i][jt] - mu) * rstd * g4[jt] + bt4[jt];
    }
  }
}

extern "C" void kernel_launch(void* const* d_in, const int* in_sizes, int n_in,
                              void* d_out, int out_size, void* d_ws, size_t ws_size,
                              hipStream_t stream) {
  const float* x       = (const float*)d_in[0];
  const int*   pre_m   = (const int*)d_in[1];
  const int*   post_m  = (const int*)d_in[2];
  const float* in_w    = (const float*)d_in[3];
  const float* in_b    = (const float*)d_in[4];
  const float* out_w   = (const float*)d_in[5];
  const float* out_b   = (const float*)d_in[6];
  const float* gamma   = (const float*)d_in[7];
  const float* beta    = (const float*)d_in[8];
  float* out   = (float*)d_out;                       // [B,N,E]
  float* attnw = out + (size_t)BB * NN * EE;          // [B,N,N]
  ushort_t* Q   = (ushort_t*)d_ws;                    // bf16 [B,H,N,32]
  ushort_t* K   = Q  + (size_t)BB * HH * NN * HDD;    // bf16 [B,H,N,32]
  ushort_t* Vt  = K  + (size_t)BB * HH * NN * HDD;    // bf16 [B,H,32,N]
  ushort_t* xb  = Vt + (size_t)BB * HH * NN * HDD;    // bf16 [B*N, E]
  ushort_t* wib = xb + (size_t)BB * NN * EE;          // bf16 [768, 256]
  ushort_t* wob = wib + (size_t)3 * EE * EE;          // bf16 [256, 256]
  ull_t* mbits  = (ull_t*)(wob + (size_t)EE * EE);    // 1 bit per pre_mask elem, 8.4 MB

  const int NCVT = BB * NN * EE / 4 + 3 * EE * EE / 4 + EE * EE / 4;
  cvt_all<<<dim3((NCVT + 255) / 256), dim3(256), 0, stream>>>(x, in_w, out_w, xb, wib, wob);
  qkv_mfma<<<dim3(768), dim3(256), 0, stream>>>(xb, wib, in_b, Q, K, Vt, pre_m, mbits);
  attn_fused<<<dim3(1024), dim3(256), 0, stream>>>(Q, K, Vt, (const uint_t*)mbits, wob, x,
                                                   out_b, post_m, gamma, beta, out, attnw);
}

// Round 7
// 461.472 us; speedup vs baseline: 1.6572x; 1.6572x over previous
//
#include <hip/hip_runtime.h>

#define BB 32
#define NN 512
#define EE 256
#define HH 8
#define HDD 32

typedef __attribute__((ext_vector_type(4))) float f32x4;
typedef __attribute__((ext_vector_type(8))) short s16x8;
typedef unsigned short ushort_t;
typedef unsigned int uint_t;

__device__ __forceinline__ ushort_t f2bf(float f) {
  union { float f; uint_t u; } v; v.f = f;
  uint_t r = v.u + 0x7fffu + ((v.u >> 16) & 1u);
  return (ushort_t)(r >> 16);
}
__device__ __forceinline__ uint_t pk2(float a, float b) {
  return (uint_t)f2bf(a) | ((uint_t)f2bf(b) << 16);
}
__device__ __forceinline__ float bf2f(ushort_t u) {
  union { uint_t u; float f; } v; v.u = ((uint_t)u) << 16;
  return v.f;
}

// ---------------- Kernel 0: fp32 -> bf16 convert (x, in_w, out_w in one grid) ----------------
__global__ __launch_bounds__(256) void cvt_all(
    const float* __restrict__ x, const float* __restrict__ w1, const float* __restrict__ w2,
    ushort_t* __restrict__ xb, ushort_t* __restrict__ w1b, ushort_t* __restrict__ w2b) {
  const int NX = BB * NN * EE / 4;     // 1048576
  const int NW1 = 3 * EE * EE / 4;     // 49152
  const int NW2 = EE * EE / 4;         // 16384
  int i = blockIdx.x * 256 + threadIdx.x;
  const float* src; ushort_t* dst; int j;
  if (i < NX) { src = x; dst = xb; j = i; }
  else if (i < NX + NW1) { src = w1; dst = w1b; j = i - NX; }
  else if (i < NX + NW1 + NW2) { src = w2; dst = w2b; j = i - NX - NW1; }
  else return;
  float4 v = ((const float4*)src)[j];
  uint2 p; p.x = pk2(v.x, v.y); p.y = pk2(v.z, v.w);
  ((uint2*)dst)[j] = p;
}

// ---------------- Kernel 1: QKV projection (bf16 MFMA GEMM) ----------------
// 128x128 tile, 4 waves 2x2, BK=32. Q,K head-major [B,H,N,32]; V transposed [B,H,32,N].
__global__ __launch_bounds__(256) void qkv_mfma(
    const ushort_t* __restrict__ xb, const ushort_t* __restrict__ wb,
    const float* __restrict__ bias,
    ushort_t* __restrict__ Q, ushort_t* __restrict__ K, ushort_t* __restrict__ Vt) {
  __shared__ ushort_t sA[128][40];
  __shared__ ushort_t sB[128][40];
  int t = threadIdx.x;
  int bj = blockIdx.x % 6, bm = blockIdx.x / 6;
  int m0 = bm * 128, j0 = bj * 128;
  int w4 = t >> 6, lane = t & 63, quad = lane >> 4, l16 = lane & 15;
  int wy = w4 >> 1, wx = w4 & 1;
  f32x4 acc[4][4];
  #pragma unroll
  for (int a = 0; a < 4; a++)
    #pragma unroll
    for (int b = 0; b < 4; b++) acc[a][b] = (f32x4){0.f, 0.f, 0.f, 0.f};
  int sr2 = t >> 2, sc2 = (t & 3) * 8;
  for (int kk = 0; kk < 256; kk += 32) {
    __syncthreads();
    #pragma unroll
    for (int p = 0; p < 2; p++) {
      int r = sr2 + 64 * p;
      *(s16x8*)&sA[r][sc2] = *(const s16x8*)&xb[(size_t)(m0 + r) * 256 + kk + sc2];
      *(s16x8*)&sB[r][sc2] = *(const s16x8*)&wb[(size_t)(j0 + r) * 256 + kk + sc2];
    }
    __syncthreads();
    s16x8 af[4], bf[4];
    #pragma unroll
    for (int mt = 0; mt < 4; mt++)
      af[mt] = *(const s16x8*)&sA[wy * 64 + mt * 16 + l16][quad * 8];
    #pragma unroll
    for (int jt = 0; jt < 4; jt++)
      bf[jt] = *(const s16x8*)&sB[wx * 64 + jt * 16 + l16][quad * 8];
    #pragma unroll
    for (int mt = 0; mt < 4; mt++)
      #pragma unroll
      for (int jt = 0; jt < 4; jt++)
        acc[mt][jt] = __builtin_amdgcn_mfma_f32_16x16x32_bf16(af[mt], bf[jt], acc[mt][jt], 0, 0, 0);
  }
  #pragma unroll
  for (int jt = 0; jt < 4; jt++) {
    int j = j0 + wx * 64 + jt * 16 + l16;
    int which = j >> 8, e0 = j & 255, h = e0 >> 5, d0 = e0 & 31;
    float b = bias[j];
    #pragma unroll
    for (int mt = 0; mt < 4; mt++) {
      #pragma unroll
      for (int r = 0; r < 4; r++) {
        int m = m0 + wy * 64 + mt * 16 + quad * 4 + r;
        int bi = m >> 9, n = m & 511;
        ushort_t val = f2bf(acc[mt][jt][r] + b);
        if (which == 2) {
          Vt[((size_t)(bi * 8 + h) * 32 + d0) * 512 + n] = val;
        } else {
          ushort_t* dst = (which == 0) ? Q : K;
          dst[((size_t)(bi * 8 + h) * 512 + n) * 32 + d0] = val;
        }
      }
    }
  }
}

// ---------------- Kernel 2: fused attention + out-proj + mask + residual + LN ----------------
// block = (b, 16-q tile), 1024 blocks, 4 waves; wave w owns keys [w*128, w*128+128)
// Masks prefetched into registers per head, ahead of the dependent exp.
__global__ __launch_bounds__(256, 4) void attn_fused(
    const ushort_t* __restrict__ Q, const ushort_t* __restrict__ K,
    const ushort_t* __restrict__ Vt, const int* __restrict__ pre_mask,
    const ushort_t* __restrict__ wob, const float* __restrict__ x,
    const float* __restrict__ out_b, const int* __restrict__ post_mask,
    const float* __restrict__ gamma, const float* __restrict__ beta,
    float* __restrict__ out, float* __restrict__ attnw) {
  __shared__ ushort_t sP[4][16 * 132];   // wave-private unnormalized e (bf16)
  __shared__ float sSum[2][4][16];       // double-buffered per-head row sums
  __shared__ float sO[4][16 * 33];       // per-wave PV partials
  __shared__ ushort_t sO16[16 * 260];    // assembled O tile (bf16, A-layout)
  __shared__ float sRed1[16][4];         // LN reduce
  __shared__ float sRed2[16][4];

  int t = threadIdx.x;
  int bb = blockIdx.x >> 5;
  int q0 = (blockIdx.x & 31) << 4;
  int w = t >> 6, lane = t & 63, quad = lane >> 4, l16 = lane & 15;
  int kbase = w * 128;
  const float scale = 0.17677669529663687f;  // 1/sqrt(32)
  ushort_t* mysP = &sP[w][0];

  // head-mean accumulators packed as bf16 pairs
  uint_t wm[16];
  #pragma unroll
  for (int i = 0; i < 16; i++) wm[i] = 0u;

  for (int h = 0; h < 8; h++) {
    size_t base = ((size_t)(bb * 8 + h) * 512) * 32;
    const int* mbase = pre_mask + ((size_t)(bb * 8 + h) * 512 + q0) * 512;

    // ---- prefetch this head's 32 mask dwords (issued before any dependent use) ----
    int mreg[32];
    #pragma unroll
    for (int t8 = 0; t8 < 8; t8++)
      #pragma unroll
      for (int i = 0; i < 4; i++)
        mreg[t8 * 4 + i] = mbase[(quad * 4 + i) * 512 + kbase + t8 * 16 + l16];

    // Q A-frag direct from global
    s16x8 afrag = *(const s16x8*)&Q[base + (size_t)(q0 + l16) * 32 + quad * 8];

    // ---- scores + exp + wave-private sP + partial sums ----
    float psum[4] = {0.f, 0.f, 0.f, 0.f};
    #pragma unroll
    for (int t8 = 0; t8 < 8; t8++) {
      int n0 = kbase + t8 * 16;
      s16x8 bfrag = *(const s16x8*)&K[base + (size_t)(n0 + l16) * 32 + quad * 8];
      f32x4 acc = {0.f, 0.f, 0.f, 0.f};
      acc = __builtin_amdgcn_mfma_f32_16x16x32_bf16(afrag, bfrag, acc, 0, 0, 0);
      #pragma unroll
      for (int i = 0; i < 4; i++) {
        float e = mreg[t8 * 4 + i] ? 0.f : __expf(acc[i] * scale);
        mysP[(quad * 4 + i) * 132 + t8 * 16 + l16] = f2bf(e);
        psum[i] += e;
      }
    }
    #pragma unroll
    for (int i = 0; i < 4; i++) {
      float s = psum[i];
      s += __shfl_xor(s, 1, 64);
      s += __shfl_xor(s, 2, 64);
      s += __shfl_xor(s, 4, 64);
      s += __shfl_xor(s, 8, 64);
      psum[i] = s;
    }
    if (l16 == 0) {
      #pragma unroll
      for (int i = 0; i < 4; i++) sSum[h & 1][w][quad * 4 + i] = psum[i];
    }
    __syncthreads();   // B2: sSum ready (also fences prior head's epilogue reads of sO)

    // ---- head-mean weights: re-read own sP, accumulate in packed bf16 ----
    float inv[4];
    #pragma unroll
    for (int i = 0; i < 4; i++) {
      int r = quad * 4 + i;
      inv[i] = 0.125f / (sSum[h & 1][0][r] + sSum[h & 1][1][r] + sSum[h & 1][2][r] + sSum[h & 1][3][r]);
    }
    #pragma unroll
    for (int i = 0; i < 4; i++) {
      #pragma unroll
      for (int t4 = 0; t4 < 4; t4++) {
        float a0 = inv[i] * bf2f(mysP[(quad * 4 + i) * 132 + (2 * t4) * 16 + l16]);
        float a1 = inv[i] * bf2f(mysP[(quad * 4 + i) * 132 + (2 * t4 + 1) * 16 + l16]);
        uint_t cur = wm[i * 4 + t4];
        wm[i * 4 + t4] = pk2(bf2f((ushort_t)(cur & 0xffffu)) + a0,
                             bf2f((ushort_t)(cur >> 16)) + a1);
      }
    }

    // ---- PV over own 128-k slice (unnormalized); wave-private sP, no barrier ----
    f32x4 oacc[2];
    oacc[0] = (f32x4){0.f, 0.f, 0.f, 0.f};
    oacc[1] = (f32x4){0.f, 0.f, 0.f, 0.f};
    #pragma unroll
    for (int ks = 0; ks < 4; ks++) {
      s16x8 pa = *(const s16x8*)&mysP[l16 * 132 + ks * 32 + quad * 8];
      #pragma unroll
      for (int dt = 0; dt < 2; dt++) {
        s16x8 vb = *(const s16x8*)&Vt[base + (size_t)(dt * 16 + l16) * 512 + kbase + ks * 32 + quad * 8];
        oacc[dt] = __builtin_amdgcn_mfma_f32_16x16x32_bf16(pa, vb, oacc[dt], 0, 0, 0);
      }
    }
    #pragma unroll
    for (int dt = 0; dt < 2; dt++)
      #pragma unroll
      for (int i = 0; i < 4; i++)
        sO[w][(quad * 4 + i) * 33 + dt * 16 + l16] = oacc[dt][i];
    __syncthreads();   // B3: sO ready

    // ---- combine waves, normalize, stash O tile in LDS (bf16 A-layout) ----
    {
      int r = t >> 4;
      int c = (t & 15) * 2;
      float s0 = sO[0][r * 33 + c] + sO[1][r * 33 + c] + sO[2][r * 33 + c] + sO[3][r * 33 + c];
      float s1 = sO[0][r * 33 + c + 1] + sO[1][r * 33 + c + 1] + sO[2][r * 33 + c + 1] + sO[3][r * 33 + c + 1];
      float invr = 1.0f / (sSum[h & 1][0][r] + sSum[h & 1][1][r] + sSum[h & 1][2][r] + sSum[h & 1][3][r]);
      *(uint_t*)&sO16[r * 260 + h * 32 + c] = pk2(s0 * invr, s1 * invr);
    }
  }

  // ---- head-averaged attention weights (unpack bf16 pairs) ----
  {
    float* arow = attnw + (size_t)(bb * 512 + q0) * 512;
    #pragma unroll
    for (int i = 0; i < 4; i++) {
      #pragma unroll
      for (int t4 = 0; t4 < 4; t4++) {
        uint_t c = wm[i * 4 + t4];
        arow[(quad * 4 + i) * 512 + kbase + (2 * t4) * 16 + l16] = bf2f((ushort_t)(c & 0xffffu));
        arow[(quad * 4 + i) * 512 + kbase + (2 * t4 + 1) * 16 + l16] = bf2f((ushort_t)(c >> 16));
      }
    }
  }
  __syncthreads();   // Bf: sO16 complete

  // ---- fused out-proj: wave w owns cols [w*64, w*64+64) ----
  int jr0 = w * 64;
  f32x4 pacc[4];
  #pragma unroll
  for (int jt = 0; jt < 4; jt++) pacc[jt] = (f32x4){0.f, 0.f, 0.f, 0.f};
  #pragma unroll
  for (int kc = 0; kc < 8; kc++) {
    s16x8 pa = *(const s16x8*)&sO16[l16 * 260 + kc * 32 + quad * 8];
    #pragma unroll
    for (int jt = 0; jt < 4; jt++) {
      s16x8 bf = *(const s16x8*)&wob[(size_t)(jr0 + jt * 16 + l16) * 256 + kc * 32 + quad * 8];
      pacc[jt] = __builtin_amdgcn_mfma_f32_16x16x32_bf16(pa, bf, pacc[jt], 0, 0, 0);
    }
  }

  // ---- post-mask + residual + LayerNorm ----
  float g4[4], bt4[4], ob4[4];
  #pragma unroll
  for (int jt = 0; jt < 4; jt++) {
    int j = jr0 + jt * 16 + l16;
    g4[jt] = gamma[j]; bt4[jt] = beta[j]; ob4[jt] = out_b[j];
  }
  float yv[4][4];
  #pragma unroll
  for (int i = 0; i < 4; i++) {
    int r = quad * 4 + i;
    int m = bb * 512 + q0 + r;
    bool msk = post_mask[m] != 0;
    float s1 = 0.f, s2 = 0.f;
    #pragma unroll
    for (int jt = 0; jt < 4; jt++) {
      int j = jr0 + jt * 16 + l16;
      float p = msk ? 0.f : (pacc[jt][i] + ob4[jt]);
      float yy = x[(size_t)m * 256 + j] + p;
      yv[i][jt] = yy; s1 += yy; s2 += yy * yy;
    }
    s1 += __shfl_xor(s1, 1, 64); s1 += __shfl_xor(s1, 2, 64);
    s1 += __shfl_xor(s1, 4, 64); s1 += __shfl_xor(s1, 8, 64);
    s2 += __shfl_xor(s2, 1, 64); s2 += __shfl_xor(s2, 2, 64);
    s2 += __shfl_xor(s2, 4, 64); s2 += __shfl_xor(s2, 8, 64);
    if (l16 == 0) { sRed1[r][w] = s1; sRed2[r][w] = s2; }
  }
  __syncthreads();
  #pragma unroll
  for (int i = 0; i < 4; i++) {
    int r = quad * 4 + i;
    int m = bb * 512 + q0 + r;
    float S1 = sRed1[r][0] + sRed1[r][1] + sRed1[r][2] + sRed1[r][3];
    float S2 = sRed2[r][0] + sRed2[r][1] + sRed2[r][2] + sRed2[r][3];
    float mu = S1 * (1.0f / 256.0f);
    float var = S2 * (1.0f / 256.0f) - mu * mu;
    float rstd = rsqrtf(var + 1e-5f);
    #pragma unroll
    for (int jt = 0; jt < 4; jt++) {
      int j = jr0 + jt * 16 + l16;
      out[(size_t)m * 256 + j] = (yv[i][jt] - mu) * rstd * g4[jt] + bt4[jt];
    }
  }
}

extern "C" void kernel_launch(void* const* d_in, const int* in_sizes, int n_in,
                              void* d_out, int out_size, void* d_ws, size_t ws_size,
                              hipStream_t stream) {
  const float* x       = (const float*)d_in[0];
  const int*   pre_m   = (const int*)d_in[1];
  const int*   post_m  = (const int*)d_in[2];
  const float* in_w    = (const float*)d_in[3];
  const float* in_b    = (const float*)d_in[4];
  const float* out_w   = (const float*)d_in[5];
  const float* out_b   = (const float*)d_in[6];
  const float* gamma   = (const float*)d_in[7];
  const float* beta    = (const float*)d_in[8];
  float* out   = (float*)d_out;                       // [B,N,E]
  float* attnw = out + (size_t)BB * NN * EE;          // [B,N,N]
  ushort_t* Q   = (ushort_t*)d_ws;                    // bf16 [B,H,N,32]
  ushort_t* K   = Q  + (size_t)BB * HH * NN * HDD;    // bf16 [B,H,N,32]
  ushort_t* Vt  = K  + (size_t)BB * HH * NN * HDD;    // bf16 [B,H,32,N]
  ushort_t* xb  = Vt + (size_t)BB * HH * NN * HDD;    // bf16 [B*N, E]
  ushort_t* wib = xb + (size_t)BB * NN * EE;          // bf16 [768, 256]
  ushort_t* wob = wib + (size_t)3 * EE * EE;          // bf16 [256, 256]

  const int NCVT = BB * NN * EE / 4 + 3 * EE * EE / 4 + EE * EE / 4;
  cvt_all<<<dim3((NCVT + 255) / 256), dim3(256), 0, stream>>>(x, in_w, out_w, xb, wib, wob);
  qkv_mfma<<<dim3(768), dim3(256), 0, stream>>>(xb, wib, in_b, Q, K, Vt);
  attn_fused<<<dim3(1024), dim3(256), 0, stream>>>(Q, K, Vt, pre_m, wob, x, out_b, post_m,
                                                   gamma, beta, out, attnw);
}